// Round 2
// baseline (210.671 us; speedup 1.0000x reference)
//
#include <hip/hip_runtime.h>

// LocalizationLoss: B=1048576, N=3, C=7. output (B,3,7) fp32, target (B,3,5) fp32.
// result = (5*(Sx+Sy+2*Swh) + 3*Sce - 0.5*Sbce)/(B*N) + 0.5   (scalar fp32)
//
// History: R1 per-block partials 59us. R2 wave-private LDS 62us. R3 gl_lds+dbuf
// 62us. R5 32-row shots 58us. R6 4-shot rotate + NT ~55us (demand BW pinned
// ~2.6 TB/s: global_load_lds has no dest reg -> compiler must vmcnt(0)-drain
// before dependent ds_reads, killing the prefetch). R7 lane-per-row float4
// direct loads CRASHED: 84B row pitch -> misaligned dwordx4 (UB, mem fault).
// R8: T14 reg-staging. Wave's contiguous 64-row region loaded as coalesced
// 16B-ALIGNED float4s into REGISTERS (wave base row is a 256-multiple ->
// row0*84 and row0*60 are 16B-divisible), ds_write to wave-private LDS, then
// the verified R6 row math from LDS on all 64 lanes. Register destinations
// give counted vmcnt(10) waits: next batch's loads stay in flight across the
// current batch's LDS-write + compute. Single LDS buffer/wave (DS ops are
// in-order per wave -> WAR safe). 2 reg batches ping-pong, 1 batch prefetch.

#define NBLK 1024            // 1024 blocks x 4 waves x 4 batches x 64 rows = B
#define INV_BN (1.0f / 3145728.0f)

// Per wave-batch: out = 64*21 floats = 336 float4; tgt = 64*15 = 240 float4.
struct Batch { float4 o[6]; float4 t[4]; };

__device__ __forceinline__ void ld_batch(const float4* __restrict__ o4,
                                         const float4* __restrict__ t4,
                                         int lane, Batch& b) {
  b.o[0] = o4[lane      ];
  b.o[1] = o4[lane +  64];
  b.o[2] = o4[lane + 128];
  b.o[3] = o4[lane + 192];
  b.o[4] = o4[lane + 256];
  if (lane < 16) b.o[5] = o4[lane + 320];   // 320..335
  b.t[0] = t4[lane      ];
  b.t[1] = t4[lane +  64];
  b.t[2] = t4[lane + 128];
  if (lane < 48) b.t[3] = t4[lane + 192];   // 192..239
}

__device__ __forceinline__ void wr_batch(float* so, float* st, int lane,
                                         const Batch& b) {
  float4* so4 = (float4*)so;
  float4* st4 = (float4*)st;
  so4[lane      ] = b.o[0];
  so4[lane +  64] = b.o[1];
  so4[lane + 128] = b.o[2];
  so4[lane + 192] = b.o[3];
  so4[lane + 256] = b.o[4];
  if (lane < 16) so4[lane + 320] = b.o[5];
  st4[lane      ] = b.t[0];
  st4[lane +  64] = b.t[1];
  st4[lane + 128] = b.t[2];
  if (lane < 48) st4[lane + 192] = b.t[3];
}

// Row math from LDS; all 64 lanes active (row = lane). Strides 21/15 odd ->
// lanes l and l+32 alias the same bank (2-way, free per m136); within a
// half-wave conflict-free.
__device__ __forceinline__ float compute_row(const float* so, const float* st,
                                             int lane) {
  const float* o = so + lane * 21;
  const float* t = st + lane * 15;
  float pbce = 1.f, sx = 0.f, sy = 0.f, swh = 0.f, sel = 0.f;
  float Lg[3][3];
  int cls[3];
  #pragma unroll
  for (int n = 0; n < 3; ++n) {
    const float tt = t[n * 5 + 0];
    const bool mk = (tt != 0.f);
    const float m = mk ? 1.f : 0.f;
    const float p = o[n * 7 + 0];
    pbce *= mk ? p : 1.f - p;               // 3 logs -> 1
    const float dx = o[n * 7 + 1] * m - t[n * 5 + 1];
    sx += dx * dx;
    const float dy = o[n * 7 + 2] * m - t[n * 5 + 2];
    sy += dy * dy;
    const float o3 = o[n * 7 + 3], t3 = t[n * 5 + 3];
    swh += t3 + (mk ? (o3 - 2.f * __builtin_sqrtf(o3 * t3)) : 0.f);
    Lg[n][0] = o[n * 7 + 4] * m;
    Lg[n][1] = o[n * 7 + 5] * m;
    Lg[n][2] = o[n * 7 + 6] * m;
    cls[n] = (int)t[n * 5 + 4];
  }
  float prodS = 1.f;
  #pragma unroll
  for (int j = 0; j < 3; ++j) {
    prodS *= __expf(Lg[0][j]) + __expf(Lg[1][j]) + __expf(Lg[2][j]);
    const int idx = cls[j];
    sel += (idx == 0) ? Lg[0][j] : ((idx == 1) ? Lg[1][j] : Lg[2][j]);
  }
  return 5.f * (sx + sy + 2.f * swh) + 3.f * (__logf(prodS) - sel)
         - 0.5f * __logf(pbce);
}

__global__ __launch_bounds__(256, 3) void loc_loss_kernel(
    const float* __restrict__ gout, const float* __restrict__ gtgt,
    float* __restrict__ ws) {
  // Wave-private single buffers: 4 x (5376 + 3840) B = 36864 B/block.
  __shared__ alignas(16) float sO[4][64 * 21];
  __shared__ alignas(16) float sT[4][64 * 15];

  const int tid = threadIdx.x;
  const int w = tid >> 6;
  const int lane = tid & 63;
  const size_t wg = (size_t)blockIdx.x * 4 + w;     // 4096 waves total
  // Wave region: 256 rows. out base float4 = wg*256*21/4 = wg*1344 (16B-aligned
  // since 256*84 % 16 == 0); tgt base = wg*960. Batch strides: 336 / 240.
  const float4* o4 = (const float4*)gout + wg * 1344;
  const float4* t4 = (const float4*)gtgt + wg * 960;
  float* so = sO[w];
  float* st = sT[w];

  Batch A, B;
  float acc = 0.f;
  // Pipeline: loads of batch k+1 in flight across write+compute of batch k.
  ld_batch(o4,       t4,       lane, A);
  ld_batch(o4 + 336, t4 + 240, lane, B);
  wr_batch(so, st, lane, A);                 // waits only A's loads (vmcnt(10))
  acc += compute_row(so, st, lane);
  ld_batch(o4 + 672, t4 + 480, lane, A);
  wr_batch(so, st, lane, B);                 // DS in-order: after batch0 reads
  acc += compute_row(so, st, lane);
  ld_batch(o4 + 1008, t4 + 720, lane, B);
  wr_batch(so, st, lane, A);
  acc += compute_row(so, st, lane);
  wr_batch(so, st, lane, B);
  acc += compute_row(so, st, lane);

  #pragma unroll
  for (int off = 32; off > 0; off >>= 1) acc += __shfl_down(acc, off, 64);
  if (lane == 0) ws[wg] = acc;
}

__global__ __launch_bounds__(256) void loc_loss_finalize(
    const float* __restrict__ ws, float* __restrict__ out) {
  __shared__ float s_wave[4];
  const int tid = threadIdx.x;
  const float4* w4 = (const float4*)ws;  // 4096 partials = 1024 float4
  float acc = 0.f;
  #pragma unroll
  for (int i = 0; i < 4; ++i) {
    float4 v = w4[tid + 256 * i];
    acc += (v.x + v.y) + (v.z + v.w);
  }
  #pragma unroll
  for (int off = 32; off > 0; off >>= 1) acc += __shfl_down(acc, off, 64);
  if ((tid & 63) == 0) s_wave[tid >> 6] = acc;
  __syncthreads();
  if (tid == 0) {
    out[0] = (s_wave[0] + s_wave[1] + s_wave[2] + s_wave[3]) * INV_BN + 0.5f;
  }
}

extern "C" void kernel_launch(void* const* d_in, const int* in_sizes, int n_in,
                              void* d_out, int out_size, void* d_ws, size_t ws_size,
                              hipStream_t stream) {
  const float* gout = (const float*)d_in[0];  // (B,3,7)
  const float* gtgt = (const float*)d_in[1];  // (B,3,5)
  float* ws = (float*)d_ws;                   // 4096 floats = 16 KB
  float* out = (float*)d_out;

  loc_loss_kernel<<<NBLK, 256, 0, stream>>>(gout, gtgt, ws);
  loc_loss_finalize<<<1, 256, 0, stream>>>(ws, out);
}

// Round 3
// 178.532 us; speedup vs baseline: 1.1800x; 1.1800x over previous
//
#include <hip/hip_runtime.h>

// LocalizationLoss: B=1048576, N=3, C=7. output (B,3,7) fp32, target (B,3,5) fp32.
// result = (5*(Sx+Sy+2*Swh) + 3*Sce - 0.5*Sbce)/(B*N) + 0.5   (scalar fp32)
//
// History: R1 59us partials. R2 wave-private LDS 62us. R3 gl_lds dbuf 62us.
// R5 32-row shots 58us. R6 gl_lds 4-shot rotate ~55us, demand pinned 2.6 TB/s.
// R7 lane-per-row float4: CRASH (84B pitch -> misaligned dwordx4). R8 64-row
// reg-staged batches: SPILLED (VGPR=80 = just the 2 Batch structs; 114 MB
// scratch writes, occupancy 8 waves/CU, 96us). Counted-vmcnt theory untested.
// R9: same reg-staging idea, sized to provably fit registers:
//  - 32-row batches: 5 named float4 (20 VGPR) each, no structs/arrays.
//  - depth-3 slot rotation (A,B,C): ~2 batches always in flight per wave;
//    compiler emits counted vmcnt (dest regs are tracked precisely).
//  - SINGLE wave-private LDS buffer (DS ops in-order per wave -> WAR-safe),
//    18.4 KB/block -> occupancy VGPR-bound ~16 waves/CU.
//  - compute: lanes 0-31, row=lane, strides 21/15 odd -> conflict-free.
// In-flight/CU ~16 waves x 9 KB >> 23 KB needed at 900cy/6.3TB/s.

#define NBLK 1024            // 1024 blk x 4 waves x 8 batches x 32 rows = B
#define INV_BN (1.0f / 3145728.0f)

// Per 32-row batch: out = 168 float4 (2 full + 40-lane), tgt = 120 (1 + 56).
#define LD_BATCH(s, b)                                            \
  {                                                               \
    const float4* po = o4 + (b) * 168;                            \
    const float4* pt = t4 + (b) * 120;                            \
    s##o0 = po[lane];                                             \
    s##o1 = po[lane + 64];                                        \
    if (lane < 40) s##o2 = po[lane + 128];                        \
    s##t0 = pt[lane];                                             \
    if (lane < 56) s##t1 = pt[lane + 64];                         \
  }

#define WR_BATCH(s)                                               \
  {                                                               \
    so4[lane] = s##o0;                                            \
    so4[lane + 64] = s##o1;                                       \
    if (lane < 40) so4[lane + 128] = s##o2;                       \
    st4[lane] = s##t0;                                            \
    if (lane < 56) st4[lane + 64] = s##t1;                        \
  }

// Row math from LDS; lanes 0..31 (row = lane). 21/15 coprime with 32 banks.
__device__ __forceinline__ float compute_row(const float* so, const float* st,
                                             int lane) {
  const float* o = so + lane * 21;
  const float* t = st + lane * 15;
  float pbce = 1.f, sx = 0.f, sy = 0.f, swh = 0.f, sel = 0.f;
  float Lg[3][3];
  int cls[3];
  #pragma unroll
  for (int n = 0; n < 3; ++n) {
    const float tt = t[n * 5 + 0];
    const bool mk = (tt != 0.f);
    const float m = mk ? 1.f : 0.f;
    const float p = o[n * 7 + 0];
    pbce *= mk ? p : 1.f - p;               // 3 logs -> 1
    const float dx = o[n * 7 + 1] * m - t[n * 5 + 1];
    sx += dx * dx;
    const float dy = o[n * 7 + 2] * m - t[n * 5 + 2];
    sy += dy * dy;
    const float o3 = o[n * 7 + 3], t3 = t[n * 5 + 3];
    swh += t3 + (mk ? (o3 - 2.f * __builtin_sqrtf(o3 * t3)) : 0.f);
    Lg[n][0] = o[n * 7 + 4] * m;
    Lg[n][1] = o[n * 7 + 5] * m;
    Lg[n][2] = o[n * 7 + 6] * m;
    cls[n] = (int)t[n * 5 + 4];
  }
  float prodS = 1.f;
  #pragma unroll
  for (int j = 0; j < 3; ++j) {
    prodS *= __expf(Lg[0][j]) + __expf(Lg[1][j]) + __expf(Lg[2][j]);
    const int idx = cls[j];
    sel += (idx == 0) ? Lg[0][j] : ((idx == 1) ? Lg[1][j] : Lg[2][j]);
  }
  return 5.f * (sx + sy + 2.f * swh) + 3.f * (__logf(prodS) - sel)
         - 0.5f * __logf(pbce);
}

__global__ __launch_bounds__(256, 3) void loc_loss_kernel(
    const float* __restrict__ gout, const float* __restrict__ gtgt,
    float* __restrict__ ws) {
  // Single wave-private 32-row buffer: 2688 + 1920 B = 4608 B x 4 = 18432 B.
  __shared__ alignas(16) float sO[4][32 * 21];
  __shared__ alignas(16) float sT[4][32 * 15];

  const int tid = threadIdx.x;
  const int w = tid >> 6;
  const int lane = tid & 63;
  const size_t wg = (size_t)blockIdx.x * 4 + w;     // 4096 waves, 256 rows each
  // out base float4 = wg*256*21/4 = wg*1344 (16B-aligned); tgt = wg*960.
  const float4* o4 = (const float4*)gout + wg * 1344;
  const float4* t4 = (const float4*)gtgt + wg * 960;
  float4* so4 = (float4*)sO[w];
  float4* st4 = (float4*)sT[w];
  const float* so = sO[w];
  const float* st = sT[w];

  float4 Ao0, Ao1, Ao2, At0, At1;   // slot A: 20 VGPR
  float4 Bo0, Bo1, Bo2, Bt0, Bt1;   // slot B
  float4 Co0, Co1, Co2, Ct0, Ct1;   // slot C
  float acc = 0.f;

  // Depth-3 pipeline over 8 batches: WR(x) waits only x's 5 loads (counted
  // vmcnt; ~2 batches remain in flight), LD(x, k+3) refills the slot, then
  // compute overlaps the outstanding loads.
  LD_BATCH(A, 0); LD_BATCH(B, 1); LD_BATCH(C, 2);
  WR_BATCH(A); LD_BATCH(A, 3);
  if (lane < 32) acc += compute_row(so, st, lane);
  WR_BATCH(B); LD_BATCH(B, 4);
  if (lane < 32) acc += compute_row(so, st, lane);
  WR_BATCH(C); LD_BATCH(C, 5);
  if (lane < 32) acc += compute_row(so, st, lane);
  WR_BATCH(A); LD_BATCH(A, 6);
  if (lane < 32) acc += compute_row(so, st, lane);
  WR_BATCH(B); LD_BATCH(B, 7);
  if (lane < 32) acc += compute_row(so, st, lane);
  WR_BATCH(C);
  if (lane < 32) acc += compute_row(so, st, lane);
  WR_BATCH(A);
  if (lane < 32) acc += compute_row(so, st, lane);
  WR_BATCH(B);
  if (lane < 32) acc += compute_row(so, st, lane);

  #pragma unroll
  for (int off = 32; off > 0; off >>= 1) acc += __shfl_down(acc, off, 64);
  if (lane == 0) ws[wg] = acc;
}

__global__ __launch_bounds__(256) void loc_loss_finalize(
    const float* __restrict__ ws, float* __restrict__ out) {
  __shared__ float s_wave[4];
  const int tid = threadIdx.x;
  const float4* w4 = (const float4*)ws;  // 4096 partials = 1024 float4
  float acc = 0.f;
  #pragma unroll
  for (int i = 0; i < 4; ++i) {
    float4 v = w4[tid + 256 * i];
    acc += (v.x + v.y) + (v.z + v.w);
  }
  #pragma unroll
  for (int off = 32; off > 0; off >>= 1) acc += __shfl_down(acc, off, 64);
  if ((tid & 63) == 0) s_wave[tid >> 6] = acc;
  __syncthreads();
  if (tid == 0) {
    out[0] = (s_wave[0] + s_wave[1] + s_wave[2] + s_wave[3]) * INV_BN + 0.5f;
  }
}

extern "C" void kernel_launch(void* const* d_in, const int* in_sizes, int n_in,
                              void* d_out, int out_size, void* d_ws, size_t ws_size,
                              hipStream_t stream) {
  const float* gout = (const float*)d_in[0];  // (B,3,7)
  const float* gtgt = (const float*)d_in[1];  // (B,3,5)
  float* ws = (float*)d_ws;                   // 4096 floats = 16 KB
  float* out = (float*)d_out;

  loc_loss_kernel<<<NBLK, 256, 0, stream>>>(gout, gtgt, ws);
  loc_loss_finalize<<<1, 256, 0, stream>>>(ws, out);
}